// Round 1
// baseline (47.177 us; speedup 1.0000x reference)
//
#include <hip/hip_runtime.h>
#include <math.h>

#define D_DIM (1 << 18)
#define NB 8
#define NQ 18
#define NACC 37   // per-batch: [0]=S, [1+k]=Z_k (k=0..17), [19+k]=X_k

#define BLOCKS_PER_ROW 64
#define THREADS 256

// ws layout (doubles): ws[b*37 + j]

__global__ __launch_bounds__(THREADS) void qc_reduce(const float* __restrict__ x,
                                                     double* __restrict__ ws)
{
    const int UROW = D_DIM / 4;                 // 65536 float4 per row
    const int USEG = UROW / BLOCKS_PER_ROW;     // 1024
    const int ITER = USEG / THREADS;            // 4

    int b   = blockIdx.x / BLOCKS_PER_ROW;
    int seg = blockIdx.x % BLOCKS_PER_ROW;
    int t   = threadIdx.x;
    const float4* rowv = (const float4*)(x + (size_t)b * D_DIM);
    int ubase = seg * USEG;

    float S = 0.f;
    float zacc[18];
    float xacc[18];
#pragma unroll
    for (int k = 0; k < 18; ++k) { zacc[k] = 0.f; xacc[k] = 0.f; }

#pragma unroll
    for (int i = 0; i < ITER; ++i) {
        int u = ubase + i * THREADS + t;        // low 8 bits of u == t
        float4 v = rowv[u];
        float vv = v.x*v.x + v.y*v.y + v.z*v.z + v.w*v.w;
        S += vv;

        // k=0: d-bit0 lives inside the float4
        zacc[0] += (v.x*v.x - v.y*v.y) + (v.z*v.z - v.w*v.w);
        xacc[0] += 2.f*(v.x*v.y + v.z*v.w);
        // k=1
        zacc[1] += (v.x*v.x + v.y*v.y) - (v.z*v.z + v.w*v.w);
        xacc[1] += 2.f*(v.x*v.z + v.y*v.w);

        // k=2..7: partner u differs in a lane bit -> shuffle
#pragma unroll
        for (int k = 2; k < 8; ++k) {
            int m = 1 << (k - 2);
            float px = __shfl_xor(v.x, m, 64);
            float py = __shfl_xor(v.y, m, 64);
            float pz = __shfl_xor(v.z, m, 64);
            float pw = __shfl_xor(v.w, m, 64);
            xacc[k] += v.x*px + v.y*py + v.z*pz + v.w*pw;
            zacc[k] += ((u >> (k - 2)) & 1) ? -vv : vv;
        }

        // k=8..17: partner float4 from global (fully cache-resident, coalesced)
#pragma unroll
        for (int k = 8; k < 18; ++k) {
            float4 p = rowv[u ^ (1 << (k - 2))];
            xacc[k] += v.x*p.x + v.y*p.y + v.z*p.z + v.w*p.w;
            zacc[k] += ((u >> (k - 2)) & 1) ? -vv : vv;
        }
    }

    // ---- block reduction of 37 scalars ----
    float acc[NACC];
    acc[0] = S;
#pragma unroll
    for (int k = 0; k < 18; ++k) { acc[1 + k] = zacc[k]; acc[19 + k] = xacc[k]; }

    __shared__ float red[4][NACC];
    int lane = t & 63, w = t >> 6;
#pragma unroll
    for (int j = 0; j < NACC; ++j) {
        float v = acc[j];
#pragma unroll
        for (int off = 32; off; off >>= 1) v += __shfl_down(v, off, 64);
        if (lane == 0) red[w][j] = v;
    }
    __syncthreads();
    if (t < NACC) {
        float s = red[0][t] + red[1][t] + red[2][t] + red[3][t];
        atomicAdd(&ws[b * NACC + t], (double)s);
    }
}

__global__ __launch_bounds__(192) void qc_finalize(const float* __restrict__ ap,
                                                   const float* __restrict__ up,
                                                   const double* __restrict__ ws,
                                                   float* __restrict__ out)
{
    __shared__ float anc2[16];
    if (threadIdx.x == 0) {
        // 4-qubit ancilla circuit: 2 layers of RY(0..3) + CRY(i,i+1)
        float vec[16];
        for (int i = 0; i < 16; ++i) vec[i] = 0.f;
        vec[0] = 1.f;
        int p = 0;
        for (int layer = 0; layer < 2; ++layer) {
            for (int i = 0; i < 4; ++i) {
                float th = ap[p++] * 0.5f;
                float c = cosf(th), s = sinf(th);
                int m = 1 << (3 - i);             // MSB-first wire convention
                for (int d0 = 0; d0 < 16; ++d0) {
                    if (d0 & m) continue;
                    float a0 = vec[d0], a1 = vec[d0 | m];
                    vec[d0]     = c*a0 - s*a1;
                    vec[d0 | m] = s*a0 + c*a1;
                }
            }
            for (int i = 0; i < 3; ++i) {
                float th = ap[p++] * 0.5f;
                float c = cosf(th), s = sinf(th);
                int mc = 1 << (3 - i), mt = 1 << (2 - i);
                for (int d0 = 0; d0 < 16; ++d0) {
                    if (!(d0 & mc) || (d0 & mt)) continue;
                    float a0 = vec[d0], a1 = vec[d0 | mt];
                    vec[d0]      = c*a0 - s*a1;
                    vec[d0 | mt] = s*a0 + c*a1;
                }
            }
        }
        for (int a = 0; a < 16; ++a) anc2[a] = vec[a] * vec[a];
    }
    __syncthreads();

    int idx = threadIdx.x;
    if (idx < NB * NQ) {
        int b = idx / NQ, q = idx % NQ;
        int k = 17 - q;                           // d-bit for qubit q (MSB-first)
        float cw = 0.f, sw = 0.f;
        for (int a = 0; a < 16; ++a) {
            float th = up[a * NQ + q];            // full angle: cos(theta), sin(theta)
            cw += anc2[a] * cosf(th);
            sw += anc2[a] * sinf(th);
        }
        double Sd = ws[b * NACC];
        double Zd = ws[b * NACC + 1 + k];
        double Xd = ws[b * NACC + 19 + k];
        out[idx] = (float)(((double)cw * Zd - (double)sw * Xd) / Sd);
    }
}

extern "C" void kernel_launch(void* const* d_in, const int* in_sizes, int n_in,
                              void* d_out, int out_size, void* d_ws, size_t ws_size,
                              hipStream_t stream)
{
    const float* x  = (const float*)d_in[0];   // (8, 262144) f32
    const float* ap = (const float*)d_in[1];   // (14,) f32
    const float* up = (const float*)d_in[2];   // (16, 18) f32
    float* out = (float*)d_out;                // (8, 18) f32
    double* ws = (double*)d_ws;

    hipMemsetAsync(d_ws, 0, NB * NACC * sizeof(double), stream);
    qc_reduce<<<NB * BLOCKS_PER_ROW, THREADS, 0, stream>>>(x, ws);
    qc_finalize<<<1, 192, 0, stream>>>(ap, up, ws, out);
}

// Round 2
// 45.095 us; speedup vs baseline: 1.0462x; 1.0462x over previous
//
#include <hip/hip_runtime.h>
#include <math.h>

#define D_DIM (1 << 18)
#define NB 8
#define NQ 18
#define NACC 37   // per block partials: [0]=S, [1+k]=Z_k (k=0..17), [19+k]=X_k

#define BLOCKS_PER_ROW 64
#define THREADS 256
#define NBLOCKS (NB * BLOCKS_PER_ROW)

// ws layout (floats): ws[block * NACC + j], block in [0, 512)
// Every slot is written unconditionally every launch -> no zero-init needed.

__global__ __launch_bounds__(THREADS) void qc_reduce(const float* __restrict__ x,
                                                     float* __restrict__ ws)
{
    const int UROW = D_DIM / 4;                 // 65536 float4 per row
    const int USEG = UROW / BLOCKS_PER_ROW;     // 1024
    const int ITER = USEG / THREADS;            // 4

    int b   = blockIdx.x / BLOCKS_PER_ROW;
    int seg = blockIdx.x % BLOCKS_PER_ROW;
    int t   = threadIdx.x;
    const float4* rowv = (const float4*)(x + (size_t)b * D_DIM);
    int ubase = seg * USEG;

    float S = 0.f;
    float zacc[18];
    float xacc[18];
#pragma unroll
    for (int k = 0; k < 18; ++k) { zacc[k] = 0.f; xacc[k] = 0.f; }

#pragma unroll
    for (int i = 0; i < ITER; ++i) {
        int u = ubase + i * THREADS + t;        // low 8 bits of u == t
        float4 v = rowv[u];
        float vv = v.x*v.x + v.y*v.y + v.z*v.z + v.w*v.w;
        S += vv;

        // k=0,1: d-bits 0..1 live inside the float4
        zacc[0] += (v.x*v.x - v.y*v.y) + (v.z*v.z - v.w*v.w);
        xacc[0] += 2.f*(v.x*v.y + v.z*v.w);
        zacc[1] += (v.x*v.x + v.y*v.y) - (v.z*v.z + v.w*v.w);
        xacc[1] += 2.f*(v.x*v.z + v.y*v.w);

        // k=2..7: partner u differs in a lane bit -> shuffle
#pragma unroll
        for (int k = 2; k < 8; ++k) {
            int m = 1 << (k - 2);
            float px = __shfl_xor(v.x, m, 64);
            float py = __shfl_xor(v.y, m, 64);
            float pz = __shfl_xor(v.z, m, 64);
            float pw = __shfl_xor(v.w, m, 64);
            xacc[k] += v.x*px + v.y*py + v.z*pz + v.w*pw;
            zacc[k] += ((u >> (k - 2)) & 1) ? -vv : vv;
        }

        // k=8..17: partner float4 from global (L2/LLC-resident, coalesced)
#pragma unroll
        for (int k = 8; k < 18; ++k) {
            float4 p = rowv[u ^ (1 << (k - 2))];
            xacc[k] += v.x*p.x + v.y*p.y + v.z*p.z + v.w*p.w;
            zacc[k] += ((u >> (k - 2)) & 1) ? -vv : vv;
        }
    }

    // ---- block reduction of 37 scalars ----
    float acc[NACC];
    acc[0] = S;
#pragma unroll
    for (int k = 0; k < 18; ++k) { acc[1 + k] = zacc[k]; acc[19 + k] = xacc[k]; }

    __shared__ float red[4][NACC];
    int lane = t & 63, w = t >> 6;
#pragma unroll
    for (int j = 0; j < NACC; ++j) {
        float v = acc[j];
#pragma unroll
        for (int off = 32; off; off >>= 1) v += __shfl_down(v, off, 64);
        if (lane == 0) red[w][j] = v;
    }
    __syncthreads();
    if (t < NACC) {
        // plain store, unique slot per block -> deterministic, no init required
        ws[blockIdx.x * NACC + t] = red[0][t] + red[1][t] + red[2][t] + red[3][t];
    }
}

__global__ __launch_bounds__(256) void qc_finalize(const float* __restrict__ ap,
                                                   const float* __restrict__ up,
                                                   const float* __restrict__ ws,
                                                   float* __restrict__ out)
{
    __shared__ float anc2[16];
    __shared__ double tot[NB][NACC];

    if (threadIdx.x == 0) {
        // 4-qubit ancilla circuit: 2 layers of RY(0..3) + CRY(i,i+1), MSB-first wires
        float vec[16];
        for (int i = 0; i < 16; ++i) vec[i] = 0.f;
        vec[0] = 1.f;
        int p = 0;
        for (int layer = 0; layer < 2; ++layer) {
            for (int i = 0; i < 4; ++i) {
                float th = ap[p++] * 0.5f;
                float c = cosf(th), s = sinf(th);
                int m = 1 << (3 - i);
                for (int d0 = 0; d0 < 16; ++d0) {
                    if (d0 & m) continue;
                    float a0 = vec[d0], a1 = vec[d0 | m];
                    vec[d0]     = c*a0 - s*a1;
                    vec[d0 | m] = s*a0 + c*a1;
                }
            }
            for (int i = 0; i < 3; ++i) {
                float th = ap[p++] * 0.5f;
                float c = cosf(th), s = sinf(th);
                int mc = 1 << (3 - i), mt = 1 << (2 - i);
                for (int d0 = 0; d0 < 16; ++d0) {
                    if (!(d0 & mc) || (d0 & mt)) continue;
                    float a0 = vec[d0], a1 = vec[d0 | mt];
                    vec[d0]      = c*a0 - s*a1;
                    vec[d0 | mt] = s*a0 + c*a1;
                }
            }
        }
        for (int a = 0; a < 16; ++a) anc2[a] = vec[a] * vec[a];
    }

    // phase A: reduce 64 block-partials per (b, j)
    for (int idx = threadIdx.x; idx < NB * NACC; idx += blockDim.x) {
        int b = idx / NACC, j = idx % NACC;
        double s = 0.0;
        const float* base = ws + (size_t)b * BLOCKS_PER_ROW * NACC + j;
#pragma unroll 8
        for (int blk = 0; blk < BLOCKS_PER_ROW; ++blk)
            s += (double)base[blk * NACC];
        tot[b][j] = s;
    }
    __syncthreads();

    // phase B: combine with ancilla weights
    int idx = threadIdx.x;
    if (idx < NB * NQ) {
        int b = idx / NQ, q = idx % NQ;
        int k = 17 - q;                           // d-bit for qubit q (MSB-first)
        float cw = 0.f, sw = 0.f;
        for (int a = 0; a < 16; ++a) {
            float th = up[a * NQ + q];
            cw += anc2[a] * cosf(th);
            sw += anc2[a] * sinf(th);
        }
        double Sd = tot[b][0];
        double Zd = tot[b][1 + k];
        double Xd = tot[b][19 + k];
        out[idx] = (float)(((double)cw * Zd - (double)sw * Xd) / Sd);
    }
}

extern "C" void kernel_launch(void* const* d_in, const int* in_sizes, int n_in,
                              void* d_out, int out_size, void* d_ws, size_t ws_size,
                              hipStream_t stream)
{
    const float* x  = (const float*)d_in[0];   // (8, 262144) f32
    const float* ap = (const float*)d_in[1];   // (14,) f32
    const float* up = (const float*)d_in[2];   // (16, 18) f32
    float* out = (float*)d_out;                // (8, 18) f32
    float* ws = (float*)d_ws;

    qc_reduce<<<NBLOCKS, THREADS, 0, stream>>>(x, ws);
    qc_finalize<<<1, 256, 0, stream>>>(ap, up, ws, out);
}

// Round 3
// 38.808 us; speedup vs baseline: 1.2157x; 1.1620x over previous
//
#include <hip/hip_runtime.h>
#include <math.h>

#define D_DIM (1 << 18)
#define NB 8
#define NQ 18
#define NACC 37            // [0]=S, [1+k]=Z_k (k=0..17), [19+k]=X_k

#define BPR 128            // blocks per row
#define THREADS 256
#define NBLOCKS (NB * BPR) // 1024
#define UROW (D_DIM / 4)   // 65536 float4 per row
#define USEG (UROW / BPR)  // 512 float4 per block
#define NITER (USEG / THREADS) // 2

__device__ __forceinline__ float dot4(float4 a, float4 b) {
    return a.x*b.x + a.y*b.y + a.z*b.z + a.w*b.w;
}

// ws layout (floats): ws[block * NACC + j]; every slot written every launch.

__global__ __launch_bounds__(THREADS) void qc_reduce(const float* __restrict__ x,
                                                     float* __restrict__ ws)
{
    int b   = blockIdx.x / BPR;
    int seg = blockIdx.x % BPR;
    int t   = threadIdx.x;
    const float4* rowv = (const float4*)(x + (size_t)b * D_DIM);

    float S = 0.f;
    float zacc[18], xacc[18];
#pragma unroll
    for (int k = 0; k < 18; ++k) { zacc[k] = 0.f; xacc[k] = 0.f; }

#pragma unroll
    for (int i = 0; i < NITER; ++i) {
        int u = seg * USEG + i * THREADS + t;   // bits0-7=t, bit8=i, bits9-15=seg
        float4 v = rowv[u];
        float vv = dot4(v, v);
        S += vv;

        // k=0,1: d-bits 0..1 inside the float4
        zacc[0] += (v.x*v.x - v.y*v.y) + (v.z*v.z - v.w*v.w);
        xacc[0] += 2.f*(v.x*v.y + v.z*v.w);
        zacc[1] += (v.x*v.x + v.y*v.y) - (v.z*v.z + v.w*v.w);
        xacc[1] += 2.f*(v.x*v.z + v.y*v.w);

        // k=2..7: u-bits 0..5 are lane bits -> shuffle (full sum, no halving)
#pragma unroll
        for (int k = 2; k < 8; ++k) {
            int m = 1 << (k - 2);
            float px = __shfl_xor(v.x, m, 64);
            float py = __shfl_xor(v.y, m, 64);
            float pz = __shfl_xor(v.z, m, 64);
            float pw = __shfl_xor(v.w, m, 64);
            xacc[k] += v.x*px + v.y*py + v.z*pz + v.w*pw;
            zacc[k] += ((u >> (k - 2)) & 1) ? -vv : vv;
        }

        // Z for k=8..17: local, always
#pragma unroll
        for (int k = 8; k < 18; ++k)
            zacc[k] += ((u >> (k - 2)) & 1) ? -vv : vv;

        // X for k=8..17 with 2x symmetry: only the bit==0 side loads the partner.
        // k=8,9: thread bits 6,7 -> wave-uniform branch
        if (((t >> 6) & 1) == 0) { float4 p = rowv[u ^ 64];  xacc[8] += dot4(v, p); }
        if (((t >> 7) & 1) == 0) { float4 p = rowv[u ^ 128]; xacc[9] += dot4(v, p); }
        // k=10: u-bit 8 == i -> compile-time
        if (i == 0) { float4 p = rowv[u ^ 256]; xacc[10] += dot4(v, p); }
        // k=11..17: u-bits 9..15 == seg bits 0..6 -> block-uniform branch
#pragma unroll
        for (int k = 11; k < 18; ++k) {
            if (((seg >> (k - 11)) & 1) == 0) {
                float4 p = rowv[u ^ (1 << (k - 2))];
                xacc[k] += dot4(v, p);
            }
        }
    }

    // double the symmetry-halved terms
#pragma unroll
    for (int k = 8; k < 18; ++k) xacc[k] *= 2.f;

    // ---- block reduction of 37 scalars ----
    float acc[NACC];
    acc[0] = S;
#pragma unroll
    for (int k = 0; k < 18; ++k) { acc[1 + k] = zacc[k]; acc[19 + k] = xacc[k]; }

    __shared__ float red[4][NACC];
    int lane = t & 63, w = t >> 6;
#pragma unroll
    for (int j = 0; j < NACC; ++j) {
        float v = acc[j];
#pragma unroll
        for (int off = 32; off; off >>= 1) v += __shfl_down(v, off, 64);
        if (lane == 0) red[w][j] = v;
    }
    __syncthreads();
    if (t < NACC)
        ws[blockIdx.x * NACC + t] = red[0][t] + red[1][t] + red[2][t] + red[3][t];
}

__global__ __launch_bounds__(256) void qc_finalize(const float* __restrict__ ap,
                                                   const float* __restrict__ up,
                                                   const float* __restrict__ ws,
                                                   float* __restrict__ out)
{
    __shared__ float anc2[16];
    __shared__ double tot[NB][NACC];
    int t = threadIdx.x;

    // ---- ancilla statevector on wave 0, lanes 0..15, via shuffles ----
    if (t < 64) {
        float c = 1.f, s = 0.f;
        if (t < 14) { float th = ap[t] * 0.5f; c = cosf(th); s = sinf(th); }
        float v = (t == 0) ? 1.f : 0.f;      // lanes 0..15 = vec; others don't matter
        int p = 0;
        for (int layer = 0; layer < 2; ++layer) {
#pragma unroll
            for (int i = 0; i < 4; ++i) {
                float cg = __shfl(c, p, 64), sg = __shfl(s, p, 64); ++p;
                int m = 1 << (3 - i);        // MSB-first wire convention
                float pv = __shfl_xor(v, m, 64);
                v = (t & m) ? (sg*pv + cg*v) : (cg*v - sg*pv);
            }
#pragma unroll
            for (int i = 0; i < 3; ++i) {
                float cg = __shfl(c, p, 64), sg = __shfl(s, p, 64); ++p;
                int mc = 1 << (3 - i), mt = 1 << (2 - i);
                float pv = __shfl_xor(v, mt, 64);
                if (t & mc) v = (t & mt) ? (sg*pv + cg*v) : (cg*v - sg*pv);
            }
        }
        if (t < 16) anc2[t] = v * v;
    }
    __syncthreads();

    // ---- phase A: sum 128 block-partials per (b, j) ----
    for (int idx = t; idx < NB * NACC; idx += 256) {
        int b = idx / NACC, j = idx % NACC;
        const float* base = ws + (size_t)b * BPR * NACC + j;
        double s0 = 0.0, s1 = 0.0;
#pragma unroll 4
        for (int blk = 0; blk < BPR; blk += 2) {
            s0 += (double)base[(size_t)blk * NACC];
            s1 += (double)base[(size_t)(blk + 1) * NACC];
        }
        tot[b][j] = s0 + s1;
    }
    __syncthreads();

    // ---- phase B: combine with ancilla weights ----
    if (t < NB * NQ) {
        int b = t / NQ, q = t % NQ;
        int k = 17 - q;                       // d-bit for qubit q (MSB-first)
        float cw = 0.f, sw = 0.f;
#pragma unroll
        for (int a = 0; a < 16; ++a) {
            float th = up[a * NQ + q];
            cw += anc2[a] * cosf(th);
            sw += anc2[a] * sinf(th);
        }
        double Sd = tot[b][0];
        double Zd = tot[b][1 + k];
        double Xd = tot[b][19 + k];
        out[t] = (float)(((double)cw * Zd - (double)sw * Xd) / Sd);
    }
}

extern "C" void kernel_launch(void* const* d_in, const int* in_sizes, int n_in,
                              void* d_out, int out_size, void* d_ws, size_t ws_size,
                              hipStream_t stream)
{
    const float* x  = (const float*)d_in[0];   // (8, 262144) f32
    const float* ap = (const float*)d_in[1];   // (14,) f32
    const float* up = (const float*)d_in[2];   // (16, 18) f32
    float* out = (float*)d_out;                // (8, 18) f32
    float* ws = (float*)d_ws;

    qc_reduce<<<NBLOCKS, THREADS, 0, stream>>>(x, ws);
    qc_finalize<<<1, 256, 0, stream>>>(ap, up, ws, out);
}